// Round 2
// baseline (985.698 us; speedup 1.0000x reference)
//
#include <hip/hip_runtime.h>
#include <hip/hip_bf16.h>
#include <math.h>

typedef __bf16 bf16;
typedef __bf16 bf16x8 __attribute__((ext_vector_type(8)));
typedef float  f32x4  __attribute__((ext_vector_type(4)));

#define NB 32768   // batch
#define NU 256     // units (= D)

#define MFMA(a,b,c) __builtin_amdgcn_mfma_f32_16x16x32_bf16((a),(b),(c),0,0,0)

static __device__ __forceinline__ bf16x8 ldfrag(const bf16* p) {
    return *reinterpret_cast<const bf16x8*>(p);
}
// load 8 consecutive fp32, round to bf16 fragment
static __device__ __forceinline__ bf16x8 ldcvt(const float* p) {
    const f32x4 a = *reinterpret_cast<const f32x4*>(p);
    const f32x4 b = *reinterpret_cast<const f32x4*>(p + 4);
    bf16x8 r;
    r[0] = (bf16)a[0]; r[1] = (bf16)a[1]; r[2] = (bf16)a[2]; r[3] = (bf16)a[3];
    r[4] = (bf16)b[0]; r[5] = (bf16)b[1]; r[6] = (bf16)b[2]; r[7] = (bf16)b[3];
    return r;
}
static __device__ __forceinline__ float sigf(float x) {
    return 1.0f / (1.0f + __expf(-x));
}

// ---------------------------------------------------------------------------
// Weight prep: fp32 sources -> K-contiguous transposed bf16 weights in ws.
//  jobs 0..7: plain transpose  dst[n*K+k] = (bf16)src[k*N+n]
//  jobs 8..9: gate concat      dst[(g*256+u)*512+k] = k<256 ? Wx[g][k][u] : Wh[g][k-256][u]
// ---------------------------------------------------------------------------
struct PrepArgs {
    const float* t_src[8];
    bf16*        t_dst[8];
    int          t_K[8];
    int          t_N[8];
    const float* gx[2];
    const float* gh[2];
    bf16*        gdst[2];
};

__global__ void k_prep(PrepArgs pa) {
    const int job = blockIdx.y;
    const int idx = blockIdx.x * 256 + threadIdx.x;
    if (job < 8) {
        const int K = pa.t_K[job], N = pa.t_N[job];
        if (idx >= K * N) return;
        const int n = idx / K, k = idx % K;          // idx == n*K + k
        pa.t_dst[job][idx] = (bf16)pa.t_src[job][k * N + n];
    } else {
        const int j = job - 8;
        if (idx >= 4 * 256 * 512) return;
        const int k = idx & 511;
        const int u = (idx >> 9) & 255;
        const int g = idx >> 17;
        pa.gdst[j][idx] = (bf16)((k < 256) ? pa.gx[j][(g * 256 + k) * 256 + u]
                                           : pa.gh[j][(g * 256 + (k - 256)) * 256 + u]);
    }
}

// ---------------------------------------------------------------------------
// s_c_hat = where(g_prev>0, h_v@Wv, h_c@Wc)   — dual GEMM, per-element select
// A operands fp32 (inline cvt), B bf16. 32x32 C tile per wave; K=256.
// ---------------------------------------------------------------------------
__global__ __launch_bounds__(64) void k_schat(
    const float* __restrict__ h_c, const float* __restrict__ h_v,
    const bf16* __restrict__ WTc, const bf16* __restrict__ WTv,
    const int* __restrict__ g_prev, bf16* __restrict__ outp)
{
    const int lane = threadIdx.x, lr = lane & 15, hi = lane >> 4;
    const int r0 = blockIdx.x * 32, c0 = blockIdx.y * 32;
    f32x4 acc1[2][2] = {}, acc2[2][2] = {};
    for (int kk = 0; kk < 8; ++kk) {
        const int kof = kk * 32 + hi * 8;
        bf16x8 a1[2], a2[2], b1[2], b2[2];
#pragma unroll
        for (int h = 0; h < 2; ++h) {
            a1[h] = ldcvt(h_c + (r0 + 16 * h + lr) * NU + kof);
            a2[h] = ldcvt(h_v + (r0 + 16 * h + lr) * NU + kof);
        }
#pragma unroll
        for (int c = 0; c < 2; ++c) {
            b1[c] = ldfrag(WTc + (c0 + 16 * c + lr) * NU + kof);
            b2[c] = ldfrag(WTv + (c0 + 16 * c + lr) * NU + kof);
        }
#pragma unroll
        for (int h = 0; h < 2; ++h)
#pragma unroll
            for (int c = 0; c < 2; ++c) {
                acc1[h][c] = MFMA(a1[h], b1[c], acc1[h][c]);
                acc2[h][c] = MFMA(a2[h], b2[c], acc2[h][c]);
            }
    }
#pragma unroll
    for (int h = 0; h < 2; ++h)
#pragma unroll
        for (int c = 0; c < 2; ++c)
#pragma unroll
            for (int r = 0; r < 4; ++r) {
                const int row = r0 + 16 * h + hi * 4 + r;
                const int col = c0 + 16 * c + lr;
                const int o = row * NU + col;
                const float v = (g_prev[o] > 0) ? acc2[h][c][r] : acc1[h][c][r];
                outp[o] = (bf16)v;
            }
}

// ---------------------------------------------------------------------------
// s_v_hat = h_v@Wv + (click>=0.5 ? h_c_n@Wc : 0) — dual GEMM, per-row gate
// h_v fp32 inline-cvt; h_c_n from bf16 ws copy.
// ---------------------------------------------------------------------------
__global__ __launch_bounds__(64) void k_svhat(
    const float* __restrict__ h_v, const bf16* __restrict__ hcnb,
    const bf16* __restrict__ WTv, const bf16* __restrict__ WTc,
    const float* __restrict__ click, bf16* __restrict__ outp)
{
    const int lane = threadIdx.x, lr = lane & 15, hi = lane >> 4;
    const int r0 = blockIdx.x * 32, c0 = blockIdx.y * 32;
    f32x4 acc1[2][2] = {}, acc2[2][2] = {};
    for (int kk = 0; kk < 8; ++kk) {
        const int kof = kk * 32 + hi * 8;
        bf16x8 a1[2], a2[2], b1[2], b2[2];
#pragma unroll
        for (int h = 0; h < 2; ++h) {
            a1[h] = ldcvt(h_v + (r0 + 16 * h + lr) * NU + kof);
            a2[h] = ldfrag(hcnb + (r0 + 16 * h + lr) * NU + kof);
        }
#pragma unroll
        for (int c = 0; c < 2; ++c) {
            b1[c] = ldfrag(WTv + (c0 + 16 * c + lr) * NU + kof);
            b2[c] = ldfrag(WTc + (c0 + 16 * c + lr) * NU + kof);
        }
#pragma unroll
        for (int h = 0; h < 2; ++h)
#pragma unroll
            for (int c = 0; c < 2; ++c) {
                acc1[h][c] = MFMA(a1[h], b1[c], acc1[h][c]);
                acc2[h][c] = MFMA(a2[h], b2[c], acc2[h][c]);
            }
    }
#pragma unroll
    for (int h = 0; h < 2; ++h)
#pragma unroll
        for (int c = 0; c < 2; ++c)
#pragma unroll
            for (int r = 0; r < 4; ++r) {
                const int row = r0 + 16 * h + hi * 4 + r;
                const int col = c0 + 16 * c + lr;
                const int o = row * NU + col;
                float v = acc1[h][c][r];
                if (click[row] >= 0.5f) v += acc2[h][c][r];
                outp[o] = (bf16)v;
            }
}

// ---------------------------------------------------------------------------
// Gates GEMM, click branch: pre[g] = [x | s_c_hat] @ WgT[g] + bx[g]
// wave tile: 32 rows x 16 u's x 4 gates. x fp32 inline-cvt, s_c_hat bf16.
// Writes fp32 outputs + bf16 ws copy of h_c_n.
// ---------------------------------------------------------------------------
__global__ __launch_bounds__(64) void k_gates_c(
    const float* __restrict__ x, const bf16* __restrict__ schat,
    const bf16* __restrict__ WgT, const float* __restrict__ bx,
    const int* __restrict__ g_prev, const float* __restrict__ s_c,
    float* __restrict__ out_scn, float* __restrict__ out_hcn,
    bf16* __restrict__ hcnb)
{
    const int lane = threadIdx.x, lr = lane & 15, hi = lane >> 4;
    const int r0 = blockIdx.x * 32, u0 = blockIdx.y * 16;
    f32x4 acc[2][4] = {};
    for (int kk = 0; kk < 16; ++kk) {
        const int kof = kk * 32 + hi * 8;
        bf16x8 a[2], bfr[4];
        if (kk < 8) {
            a[0] = ldcvt(x + (r0 + lr) * 256 + kof);
            a[1] = ldcvt(x + (r0 + 16 + lr) * 256 + kof);
        } else {
            a[0] = ldfrag(schat + (r0 + lr) * 256 + (kof - 256));
            a[1] = ldfrag(schat + (r0 + 16 + lr) * 256 + (kof - 256));
        }
#pragma unroll
        for (int g = 0; g < 4; ++g)
            bfr[g] = ldfrag(WgT + (g * 256 + u0 + lr) * 512 + kof);
#pragma unroll
        for (int h = 0; h < 2; ++h)
#pragma unroll
            for (int g = 0; g < 4; ++g)
                acc[h][g] = MFMA(a[h], bfr[g], acc[h][g]);
    }
    const int u = u0 + lr;
    const float bf_ = bx[u], bi_ = bx[256 + u];
    const float bo_ = bx[512 + u], bg_ = bx[768 + u];
#pragma unroll
    for (int h = 0; h < 2; ++h)
#pragma unroll
        for (int r = 0; r < 4; ++r) {
            const int row = r0 + 16 * h + hi * 4 + r;
            const int o = row * 256 + u;
            const float f  = sigf(acc[h][0][r] + bf_);
            const float i  = sigf(acc[h][1][r] + bi_);
            const float og = sigf(acc[h][2][r] + bo_);
            const float gt = tanhf(acc[h][3][r] + bg_);
            const bool  gp = g_prev[o] > 0;
            const float sn = i * gt + (gp ? 0.0f : f * s_c[o]);
            const float hn = og * tanhf(sn);
            out_scn[o] = sn;
            out_hcn[o] = hn;
            hcnb[o]    = (bf16)hn;
        }
}

// ---------------------------------------------------------------------------
// Gates GEMM, conversion branch: pre[g] = [x | s_v_hat] @ WgT[g] + bx[g]
// Passthrough rows (click<0.5) copy s_v/h_v EXACTLY in fp32.
// ---------------------------------------------------------------------------
__global__ __launch_bounds__(64) void k_gates_v(
    const float* __restrict__ x, const bf16* __restrict__ svhat,
    const bf16* __restrict__ WgT, const float* __restrict__ bx,
    const float* __restrict__ click, const float* __restrict__ s_v,
    const float* __restrict__ h_v,
    float* __restrict__ out_svn, float* __restrict__ out_hvn,
    float* __restrict__ out_gnw, bf16* __restrict__ hvnb)
{
    const int lane = threadIdx.x, lr = lane & 15, hi = lane >> 4;
    const int r0 = blockIdx.x * 32, u0 = blockIdx.y * 16;
    f32x4 acc[2][4] = {};
    for (int kk = 0; kk < 16; ++kk) {
        const int kof = kk * 32 + hi * 8;
        bf16x8 a[2], bfr[4];
        if (kk < 8) {
            a[0] = ldcvt(x + (r0 + lr) * 256 + kof);
            a[1] = ldcvt(x + (r0 + 16 + lr) * 256 + kof);
        } else {
            a[0] = ldfrag(svhat + (r0 + lr) * 256 + (kof - 256));
            a[1] = ldfrag(svhat + (r0 + 16 + lr) * 256 + (kof - 256));
        }
#pragma unroll
        for (int g = 0; g < 4; ++g)
            bfr[g] = ldfrag(WgT + (g * 256 + u0 + lr) * 512 + kof);
#pragma unroll
        for (int h = 0; h < 2; ++h)
#pragma unroll
            for (int g = 0; g < 4; ++g)
                acc[h][g] = MFMA(a[h], bfr[g], acc[h][g]);
    }
    const int u = u0 + lr;
    const float bf_ = bx[u], bi_ = bx[256 + u];
    const float bo_ = bx[512 + u], bg_ = bx[768 + u];
#pragma unroll
    for (int h = 0; h < 2; ++h)
#pragma unroll
        for (int r = 0; r < 4; ++r) {
            const int row = r0 + 16 * h + hi * 4 + r;
            const int o = row * 256 + u;
            const bool m = click[row] >= 0.5f;
            const float f  = sigf(acc[h][0][r] + bf_);
            const float i  = sigf(acc[h][1][r] + bi_);
            const float og = sigf(acc[h][2][r] + bo_);
            const float gt = tanhf(acc[h][3][r] + bg_);
            const float svv = s_v[o];
            const float sn = m ? (f * svv + i * gt) : svv;
            const float hn = m ? (og * tanhf(sn)) : h_v[o];
            out_svn[o] = sn;
            out_hvn[o] = hn;
            out_gnw[o] = m ? 1.0f : 0.0f;
            hvnb[o]    = (bf16)hn;
        }
}

// ---------------------------------------------------------------------------
// MLP layer: out = leaky(A @ W^T' + bias), generic over K/N (bf16 in/out in ws)
// ---------------------------------------------------------------------------
__global__ __launch_bounds__(64) void k_mlp(
    const bf16* __restrict__ A, int K,
    const bf16* __restrict__ WT, const float* __restrict__ bias,
    bf16* __restrict__ outp, int N, int ksteps)
{
    const int lane = threadIdx.x, lr = lane & 15, hi = lane >> 4;
    const int r0 = blockIdx.x * 32, c0 = blockIdx.y * 32;
    f32x4 acc[2][2] = {};
    for (int kk = 0; kk < ksteps; ++kk) {
        const int kof = kk * 32 + hi * 8;
        bf16x8 a[2], b[2];
#pragma unroll
        for (int h = 0; h < 2; ++h) a[h] = ldfrag(A + (r0 + 16 * h + lr) * K + kof);
#pragma unroll
        for (int c = 0; c < 2; ++c) b[c] = ldfrag(WT + (c0 + 16 * c + lr) * K + kof);
#pragma unroll
        for (int h = 0; h < 2; ++h)
#pragma unroll
            for (int c = 0; c < 2; ++c)
                acc[h][c] = MFMA(a[h], b[c], acc[h][c]);
    }
#pragma unroll
    for (int h = 0; h < 2; ++h)
#pragma unroll
        for (int c = 0; c < 2; ++c)
#pragma unroll
            for (int r = 0; r < 4; ++r) {
                const int row = r0 + 16 * h + hi * 4 + r;
                const int col = c0 + 16 * c + lr;
                float v = acc[h][c][r] + bias[col];
                v = v > 0.0f ? v : 0.3f * v;   // keras LeakyReLU alpha=0.3
                outp[row * N + col] = (bf16)v;
            }
}

// ---------------------------------------------------------------------------
// Final layer: sigmoid(dot(a2[b,:64], w) + bias) [* scale[b]], fp32 out
// ---------------------------------------------------------------------------
__global__ void k_final(
    const bf16* __restrict__ a2, const float* __restrict__ wv,
    const float* __restrict__ bias, const float* __restrict__ scale,
    float* __restrict__ outp)
{
    const int b = blockIdx.x * blockDim.x + threadIdx.x;
    const bf16* row = a2 + b * 64;
    float s = bias[0];
#pragma unroll
    for (int j = 0; j < 64; ++j) s += (float)row[j] * wv[j];
    float v = sigf(s);
    if (scale) v *= scale[b];
    outp[b] = v;
}

// ---------------------------------------------------------------------------
extern "C" void kernel_launch(void* const* d_in, const int* in_sizes, int n_in,
                              void* d_out, int out_size, void* d_ws, size_t ws_size,
                              hipStream_t stream)
{
    const float* x         = (const float*)d_in[0];
    const float* click     = (const float*)d_in[1];
    const float* h_c       = (const float*)d_in[2];
    const float* h_v       = (const float*)d_in[3];
    const float* s_c       = (const float*)d_in[4];
    const float* s_v       = (const float*)d_in[5];
    const int*   g_prev    = (const int*)d_in[6];
    const float* Wx_c      = (const float*)d_in[7];
    const float* bx_c      = (const float*)d_in[8];
    const float* Wh_c      = (const float*)d_in[9];
    const float* Wx_v      = (const float*)d_in[10];
    const float* bx_v      = (const float*)d_in[11];
    const float* Wh_v      = (const float*)d_in[12];
    const float* W_schat_c = (const float*)d_in[13];
    const float* W_schat_v = (const float*)d_in[14];
    const float* W_svhat_v = (const float*)d_in[15];
    const float* W_svhat_c = (const float*)d_in[16];
    const float* Wpc0 = (const float*)d_in[17];
    const float* bpc0 = (const float*)d_in[18];
    const float* Wpc1 = (const float*)d_in[19];
    const float* bpc1 = (const float*)d_in[20];
    const float* Wfcc = (const float*)d_in[21];
    const float* bfcc = (const float*)d_in[22];
    const float* Wpv0 = (const float*)d_in[23];
    const float* bpv0 = (const float*)d_in[24];
    const float* Wpv1 = (const float*)d_in[25];
    const float* bpv1 = (const float*)d_in[26];
    const float* Wfcv = (const float*)d_in[27];
    const float* bfcv = (const float*)d_in[28];

    // output layout (fp32, concatenated in return order)
    float* out     = (float*)d_out;
    float* out_hcp = out;
    float* out_hvp = out + NB;
    float* out_hcn = out + 2 * NB;
    float* out_hvn = out_hcn + NB * NU;
    float* out_scn = out_hvn + NB * NU;
    float* out_svn = out_scn + NB * NU;
    float* out_gnw = out_svn + NB * NU;

    // workspace carve (bf16 elements), ~66 MB total
    bf16* w = (bf16*)d_ws;
    bf16* WT_schat_c = w; w += 256 * 256;
    bf16* WT_schat_v = w; w += 256 * 256;
    bf16* WT_svhat_v = w; w += 256 * 256;
    bf16* WT_svhat_c = w; w += 256 * 256;
    bf16* WT_pc0     = w; w += 128 * 256;
    bf16* WT_pv0     = w; w += 128 * 256;
    bf16* WT_pc1     = w; w += 64 * 128;
    bf16* WT_pv1     = w; w += 64 * 128;
    bf16* WgT_c      = w; w += 4 * 256 * 512;
    bf16* WgT_v      = w; w += 4 * 256 * 512;
    bf16* bufA       = w; w += NB * NU;    // s_c_hat, then s_v_hat (bf16)
    bf16* hcnb       = w; w += NB * NU;    // bf16 copy of h_c_n
    bf16* hvnb       = w; w += NB * NU;    // bf16 copy of h_v_n
    bf16* bufP0      = w; w += NB * 128;   // a1_c, then a1_v
    bf16* bufP1      = w; w += NB * 64;    // a2_c, then a2_v

    PrepArgs pa;
    pa.t_src[0] = W_schat_c; pa.t_dst[0] = WT_schat_c; pa.t_K[0] = 256; pa.t_N[0] = 256;
    pa.t_src[1] = W_schat_v; pa.t_dst[1] = WT_schat_v; pa.t_K[1] = 256; pa.t_N[1] = 256;
    pa.t_src[2] = W_svhat_v; pa.t_dst[2] = WT_svhat_v; pa.t_K[2] = 256; pa.t_N[2] = 256;
    pa.t_src[3] = W_svhat_c; pa.t_dst[3] = WT_svhat_c; pa.t_K[3] = 256; pa.t_N[3] = 256;
    pa.t_src[4] = Wpc0;      pa.t_dst[4] = WT_pc0;     pa.t_K[4] = 256; pa.t_N[4] = 128;
    pa.t_src[5] = Wpv0;      pa.t_dst[5] = WT_pv0;     pa.t_K[5] = 256; pa.t_N[5] = 128;
    pa.t_src[6] = Wpc1;      pa.t_dst[6] = WT_pc1;     pa.t_K[6] = 128; pa.t_N[6] = 64;
    pa.t_src[7] = Wpv1;      pa.t_dst[7] = WT_pv1;     pa.t_K[7] = 128; pa.t_N[7] = 64;
    pa.gx[0] = Wx_c; pa.gh[0] = Wh_c; pa.gdst[0] = WgT_c;
    pa.gx[1] = Wx_v; pa.gh[1] = Wh_v; pa.gdst[1] = WgT_v;
    k_prep<<<dim3(2048, 10), 256, 0, stream>>>(pa);

    // click branch
    k_schat<<<dim3(NB / 32, NU / 32), 64, 0, stream>>>(h_c, h_v, WT_schat_c, WT_schat_v, g_prev, bufA);
    k_gates_c<<<dim3(NB / 32, NU / 16), 64, 0, stream>>>(x, bufA, WgT_c, bx_c, g_prev, s_c, out_scn, out_hcn, hcnb);
    k_mlp<<<dim3(NB / 32, 4), 64, 0, stream>>>(hcnb, 256, WT_pc0, bpc0, bufP0, 128, 8);
    k_mlp<<<dim3(NB / 32, 2), 64, 0, stream>>>(bufP0, 128, WT_pc1, bpc1, bufP1, 64, 4);
    k_final<<<NB / 256, 256, 0, stream>>>(bufP1, Wfcc, bfcc, (const float*)nullptr, out_hcp);

    // conversion branch
    k_svhat<<<dim3(NB / 32, NU / 32), 64, 0, stream>>>(h_v, hcnb, WT_svhat_v, WT_svhat_c, click, bufA);
    k_gates_v<<<dim3(NB / 32, NU / 16), 64, 0, stream>>>(x, bufA, WgT_v, bx_v, click, s_v, h_v, out_svn, out_hvn, out_gnw, hvnb);
    k_mlp<<<dim3(NB / 32, 4), 64, 0, stream>>>(hvnb, 256, WT_pv0, bpv0, bufP0, 128, 8);
    k_mlp<<<dim3(NB / 32, 2), 64, 0, stream>>>(bufP0, 128, WT_pv1, bpv1, bufP1, 64, 4);
    k_final<<<NB / 256, 256, 0, stream>>>(bufP1, Wfcv, bfcv, out_hcp, out_hvp);
}

// Round 3
// 680.857 us; speedup vs baseline: 1.4477x; 1.4477x over previous
//
#include <hip/hip_runtime.h>
#include <hip/hip_bf16.h>
#include <math.h>

typedef __bf16 bf16;
typedef __bf16 bf16x8 __attribute__((ext_vector_type(8)));
typedef float  f32x4  __attribute__((ext_vector_type(4)));

#define NB 32768   // batch
#define NU 256     // units (= D)

#define MFMA(a,b,c) __builtin_amdgcn_mfma_f32_16x16x32_bf16((a),(b),(c),0,0,0)

static __device__ __forceinline__ float sigf(float x) {
    return 1.0f / (1.0f + __expf(-x));
}

// async global->LDS, 16 B per lane. LDS dest must be thread-contiguous
// (base + tid*16); global src is per-lane arbitrary (16B-aligned).
static __device__ __forceinline__ void ld16(bf16* l, const bf16* g) {
    __builtin_amdgcn_global_load_lds(
        (const __attribute__((address_space(1))) void*)g,
        (__attribute__((address_space(3))) void*)l, 16, 0, 0);
}

static __device__ __forceinline__ bf16x8 frag(const bf16* buf, int row, int hi) {
    return *reinterpret_cast<const bf16x8*>(buf + row * 32 + hi * 8);
}

// ---------------------------------------------------------------------------
// fp32 -> bf16 activation conversion. job 0: x -> xs[:,0:256] (stride 512)
// job 1: h_v -> hv_cat[:,0:256] (stride 512); job 2: h_c -> buf256 (stride 256)
// ---------------------------------------------------------------------------
__global__ void k_cvt(const float* __restrict__ x, const float* __restrict__ h_v,
                      const float* __restrict__ h_c,
                      bf16* __restrict__ xs, bf16* __restrict__ hv_cat,
                      bf16* __restrict__ hcb)
{
    const int j = blockIdx.y;
    const int gid = blockIdx.x * 256 + threadIdx.x;   // 8-element index
    const int row = gid >> 5, col = (gid & 31) * 8;
    const float* src = (j == 0) ? x : (j == 1) ? h_v : h_c;
    bf16* dst; int stride;
    if (j == 0)      { dst = xs;     stride = 512; }
    else if (j == 1) { dst = hv_cat; stride = 512; }
    else             { dst = hcb;    stride = 256; }
    const f32x4* s4 = reinterpret_cast<const f32x4*>(src + row * 256 + col);
    const f32x4 a = s4[0], b = s4[1];
    bf16x8 o;
    o[0] = (bf16)a[0]; o[1] = (bf16)a[1]; o[2] = (bf16)a[2]; o[3] = (bf16)a[3];
    o[4] = (bf16)b[0]; o[5] = (bf16)b[1]; o[6] = (bf16)b[2]; o[7] = (bf16)b[3];
    *reinterpret_cast<bf16x8*>(dst + row * stride + col) = o;
}

// ---------------------------------------------------------------------------
// Tiled transpose: dst[c*dstr + r] = (bf16)src[r*C + c]  (fp32 src)
// 24 jobs; 32x32 tiles; block (32,8)
// ---------------------------------------------------------------------------
struct TrJobs {
    const float* src[24];
    bf16*        dst[24];
    int R[24], C[24], dstr[24];
};

__global__ void k_tr(TrJobs J) {
    __shared__ float tile[32][33];
    const int j = blockIdx.y;
    const int R = J.R[j], C = J.C[j], dstr = J.dstr[j];
    const int tilesC = C >> 5;
    const int tr = blockIdx.x / tilesC, tc = blockIdx.x % tilesC;
    if (tr >= (R >> 5)) return;
    const int r0 = tr * 32, c0 = tc * 32;
    const int tx = threadIdx.x, ty = threadIdx.y;
    const float* src = J.src[j];
    bf16* dst = J.dst[j];
#pragma unroll
    for (int i = 0; i < 4; ++i)
        tile[ty + 8 * i][tx] = src[(r0 + ty + 8 * i) * C + c0 + tx];
    __syncthreads();
#pragma unroll
    for (int i = 0; i < 4; ++i)
        dst[(c0 + ty + 8 * i) * dstr + r0 + tx] = (bf16)tile[tx][ty + 8 * i];
}

// ---------------------------------------------------------------------------
// s_c_hat = where(g_prev>0, h_v@Wv, h_c@Wc) -> xs[:,256:512] (bf16)
// dual GEMM; block tile 128x64; 4 waves each 64x32; K=256
// ---------------------------------------------------------------------------
__global__ __launch_bounds__(256) void k_schat_t(
    const bf16* __restrict__ hc, const bf16* __restrict__ hvcat,
    const bf16* __restrict__ WTc, const bf16* __restrict__ WTv,
    const int* __restrict__ g_prev, bf16* __restrict__ xs)
{
    __shared__ bf16 A1[128 * 32], A2[128 * 32], B1[64 * 32], B2[64 * 32];
    const int tid = threadIdx.x, lane = tid & 63, w = tid >> 6;
    const int lr = lane & 15, hi = lane >> 4;
    const int r0 = blockIdx.x * 128, c0 = blockIdx.y * 64;
    const int wr = w >> 1, wc = w & 1;
    const int srow = tid >> 2, skc = (tid & 3) * 8;
    f32x4 acc1[4][2] = {}, acc2[4][2] = {};
    for (int kk = 0; kk < 8; ++kk) {
        const int k0 = kk * 32;
        if (kk) __syncthreads();
        ld16(A1 + tid * 8,        hc    + (r0 + srow) * 256 + k0 + skc);
        ld16(A1 + 2048 + tid * 8, hc    + (r0 + 64 + srow) * 256 + k0 + skc);
        ld16(A2 + tid * 8,        hvcat + (r0 + srow) * 512 + k0 + skc);
        ld16(A2 + 2048 + tid * 8, hvcat + (r0 + 64 + srow) * 512 + k0 + skc);
        ld16(B1 + tid * 8,        WTc   + (c0 + srow) * 256 + k0 + skc);
        ld16(B2 + tid * 8,        WTv   + (c0 + srow) * 256 + k0 + skc);
        __syncthreads();
        bf16x8 a1[4], a2[4], b1[2], b2[2];
#pragma unroll
        for (int i = 0; i < 4; ++i) {
            a1[i] = frag(A1, wr * 64 + i * 16 + lr, hi);
            a2[i] = frag(A2, wr * 64 + i * 16 + lr, hi);
        }
#pragma unroll
        for (int jj = 0; jj < 2; ++jj) {
            b1[jj] = frag(B1, wc * 32 + jj * 16 + lr, hi);
            b2[jj] = frag(B2, wc * 32 + jj * 16 + lr, hi);
        }
#pragma unroll
        for (int i = 0; i < 4; ++i)
#pragma unroll
            for (int jj = 0; jj < 2; ++jj) {
                acc1[i][jj] = MFMA(a1[i], b1[jj], acc1[i][jj]);
                acc2[i][jj] = MFMA(a2[i], b2[jj], acc2[i][jj]);
            }
    }
#pragma unroll
    for (int i = 0; i < 4; ++i)
#pragma unroll
        for (int jj = 0; jj < 2; ++jj)
#pragma unroll
            for (int r = 0; r < 4; ++r) {
                const int row = r0 + wr * 64 + i * 16 + hi * 4 + r;
                const int col = c0 + wc * 32 + jj * 16 + lr;
                const int o = row * 256 + col;
                const float v = (g_prev[o] > 0) ? acc2[i][jj][r] : acc1[i][jj][r];
                xs[row * 512 + 256 + col] = (bf16)v;
            }
}

// ---------------------------------------------------------------------------
// s_v_hat = hv_cat @ Wsv -> xs[:,256:512]; K=512, tile 128x128, m97 structure
// ---------------------------------------------------------------------------
__global__ __launch_bounds__(256) void k_svhat_t(
    const bf16* __restrict__ hvcat, const bf16* __restrict__ Wsv,
    bf16* __restrict__ xs)
{
    __shared__ bf16 A[128 * 32], B[128 * 32];
    const int tid = threadIdx.x, lane = tid & 63, w = tid >> 6;
    const int lr = lane & 15, hi = lane >> 4;
    const int r0 = blockIdx.x * 128, c0 = blockIdx.y * 128;
    const int wr = w >> 1, wc = w & 1;
    const int srow = tid >> 2, skc = (tid & 3) * 8;
    f32x4 acc[4][4] = {};
    for (int kk = 0; kk < 16; ++kk) {
        const int k0 = kk * 32;
        if (kk) __syncthreads();
        ld16(A + tid * 8,        hvcat + (r0 + srow) * 512 + k0 + skc);
        ld16(A + 2048 + tid * 8, hvcat + (r0 + 64 + srow) * 512 + k0 + skc);
        ld16(B + tid * 8,        Wsv   + (c0 + srow) * 512 + k0 + skc);
        ld16(B + 2048 + tid * 8, Wsv   + (c0 + 64 + srow) * 512 + k0 + skc);
        __syncthreads();
        bf16x8 a[4], b[4];
#pragma unroll
        for (int i = 0; i < 4; ++i) a[i] = frag(A, wr * 64 + i * 16 + lr, hi);
#pragma unroll
        for (int jj = 0; jj < 4; ++jj) b[jj] = frag(B, wc * 64 + jj * 16 + lr, hi);
#pragma unroll
        for (int i = 0; i < 4; ++i)
#pragma unroll
            for (int jj = 0; jj < 4; ++jj)
                acc[i][jj] = MFMA(a[i], b[jj], acc[i][jj]);
    }
#pragma unroll
    for (int i = 0; i < 4; ++i)
#pragma unroll
        for (int jj = 0; jj < 4; ++jj)
#pragma unroll
            for (int r = 0; r < 4; ++r) {
                const int row = r0 + wr * 64 + i * 16 + hi * 4 + r;
                const int col = c0 + wc * 64 + jj * 16 + lr;
                xs[row * 512 + 256 + col] = (bf16)acc[i][jj][r];
            }
}

// ---------------------------------------------------------------------------
// Gates GEMM + cell update. A = xs (K=512); B tile = 4 gates x 32 u.
// Block tile 128 rows x (32u x 4g); wave: 32 rows, acc[2][8]; gates lane-local.
// mode 0 = click branch, mode 1 = conversion branch.
// ---------------------------------------------------------------------------
__global__ __launch_bounds__(256) void k_gates_t(
    const bf16* __restrict__ xs, const bf16* __restrict__ WgT,
    const float* __restrict__ bx, const float* __restrict__ click,
    const int* __restrict__ g_prev, const float* __restrict__ s_prev,
    const float* __restrict__ h_prev,
    float* __restrict__ out_s, float* __restrict__ out_h,
    float* __restrict__ out_g, bf16* __restrict__ hnb,
    bf16* __restrict__ hmask_dst, int mode)
{
    __shared__ bf16 A[128 * 32], B[128 * 32];
    const int tid = threadIdx.x, lane = tid & 63, w = tid >> 6;
    const int lr = lane & 15, hi = lane >> 4;
    const int r0 = blockIdx.x * 128, u0 = blockIdx.y * 32;
    const int srow = tid >> 2, skc = (tid & 3) * 8;
    f32x4 acc[2][8] = {};
    for (int kk = 0; kk < 16; ++kk) {
        const int k0 = kk * 32;
        if (kk) __syncthreads();
        ld16(A + tid * 8,        xs + (r0 + srow) * 512 + k0 + skc);
        ld16(A + 2048 + tid * 8, xs + (r0 + 64 + srow) * 512 + k0 + skc);
        {
            int nl = srow, g = nl >> 5, ul = nl & 31;
            ld16(B + tid * 8, WgT + (g * 256 + u0 + ul) * 512 + k0 + skc);
            nl = 64 + srow; g = nl >> 5; ul = nl & 31;
            ld16(B + 2048 + tid * 8, WgT + (g * 256 + u0 + ul) * 512 + k0 + skc);
        }
        __syncthreads();
        bf16x8 a[2], b[8];
#pragma unroll
        for (int i = 0; i < 2; ++i) a[i] = frag(A, w * 32 + i * 16 + lr, hi);
#pragma unroll
        for (int nb = 0; nb < 8; ++nb) b[nb] = frag(B, nb * 16 + lr, hi);
#pragma unroll
        for (int i = 0; i < 2; ++i)
#pragma unroll
            for (int nb = 0; nb < 8; ++nb)
                acc[i][nb] = MFMA(a[i], b[nb], acc[i][nb]);
    }
    // epilogue: gate gg lives in acc[i][gg*2 + uh]
#pragma unroll
    for (int uh = 0; uh < 2; ++uh) {
        const int u = u0 + uh * 16 + lr;
        const float bf_ = bx[u], bi_ = bx[256 + u];
        const float bo_ = bx[512 + u], bg_ = bx[768 + u];
#pragma unroll
        for (int i = 0; i < 2; ++i)
#pragma unroll
            for (int r = 0; r < 4; ++r) {
                const int row = r0 + w * 32 + i * 16 + hi * 4 + r;
                const int o = row * 256 + u;
                const float f  = sigf(acc[i][0 + uh][r] + bf_);
                const float ii = sigf(acc[i][2 + uh][r] + bi_);
                const float oo = sigf(acc[i][4 + uh][r] + bo_);
                const float gg = tanhf(acc[i][6 + uh][r] + bg_);
                if (mode == 0) {
                    const bool gp = g_prev[o] > 0;
                    const float sn = ii * gg + (gp ? 0.0f : f * s_prev[o]);
                    const float hn = oo * tanhf(sn);
                    out_s[o] = sn;
                    out_h[o] = hn;
                    hnb[o]   = (bf16)hn;
                    hmask_dst[row * 512 + 256 + u] =
                        (click[row] >= 0.5f) ? (bf16)hn : (bf16)0.0f;
                } else {
                    const bool m = click[row] >= 0.5f;
                    const float sv = s_prev[o];
                    const float sn = m ? (f * sv + ii * gg) : sv;
                    const float hn = m ? (oo * tanhf(sn)) : h_prev[o];
                    out_s[o] = sn;
                    out_h[o] = hn;
                    out_g[o] = m ? 1.0f : 0.0f;
                    hnb[o]   = (bf16)hn;
                }
            }
    }
}

// ---------------------------------------------------------------------------
// MLP layer: out = leaky(A @ WT' + bias). Tile 128 x 64; wave: 32 rows x 64 c.
// ---------------------------------------------------------------------------
__global__ __launch_bounds__(256) void k_mlp_t(
    const bf16* __restrict__ A_, int K, int ksteps,
    const bf16* __restrict__ WT, const float* __restrict__ bias,
    bf16* __restrict__ outp, int N)
{
    __shared__ bf16 A[128 * 32], B[64 * 32];
    const int tid = threadIdx.x, lane = tid & 63, w = tid >> 6;
    const int lr = lane & 15, hi = lane >> 4;
    const int r0 = blockIdx.x * 128, c0 = blockIdx.y * 64;
    const int srow = tid >> 2, skc = (tid & 3) * 8;
    f32x4 acc[2][4] = {};
    for (int kk = 0; kk < ksteps; ++kk) {
        const int k0 = kk * 32;
        if (kk) __syncthreads();
        ld16(A + tid * 8,        A_ + (r0 + srow) * K + k0 + skc);
        ld16(A + 2048 + tid * 8, A_ + (r0 + 64 + srow) * K + k0 + skc);
        ld16(B + tid * 8,        WT + (c0 + srow) * K + k0 + skc);
        __syncthreads();
        bf16x8 a[2], b[4];
#pragma unroll
        for (int i = 0; i < 2; ++i) a[i] = frag(A, w * 32 + i * 16 + lr, hi);
#pragma unroll
        for (int jj = 0; jj < 4; ++jj) b[jj] = frag(B, jj * 16 + lr, hi);
#pragma unroll
        for (int i = 0; i < 2; ++i)
#pragma unroll
            for (int jj = 0; jj < 4; ++jj)
                acc[i][jj] = MFMA(a[i], b[jj], acc[i][jj]);
    }
#pragma unroll
    for (int i = 0; i < 2; ++i)
#pragma unroll
        for (int jj = 0; jj < 4; ++jj)
#pragma unroll
            for (int r = 0; r < 4; ++r) {
                const int row = r0 + w * 32 + i * 16 + hi * 4 + r;
                const int col = c0 + jj * 16 + lr;
                float v = acc[i][jj][r] + bias[col];
                v = v > 0.0f ? v : 0.3f * v;   // keras LeakyReLU alpha=0.3
                outp[row * N + col] = (bf16)v;
            }
}

// ---------------------------------------------------------------------------
// Final layer: sigmoid(dot(a2[b,:64], w) + bias) [* scale[b]], fp32 out
// ---------------------------------------------------------------------------
__global__ void k_final(
    const bf16* __restrict__ a2, const float* __restrict__ wv,
    const float* __restrict__ bias, const float* __restrict__ scale,
    float* __restrict__ outp)
{
    const int b = blockIdx.x * blockDim.x + threadIdx.x;
    const bf16x8* rp = reinterpret_cast<const bf16x8*>(a2 + b * 64);
    float s = bias[0];
#pragma unroll
    for (int j = 0; j < 8; ++j) {
        const bf16x8 f = rp[j];
#pragma unroll
        for (int e = 0; e < 8; ++e) s += (float)f[e] * wv[j * 8 + e];
    }
    float v = sigf(s);
    if (scale) v *= scale[b];
    outp[b] = v;
}

// ---------------------------------------------------------------------------
extern "C" void kernel_launch(void* const* d_in, const int* in_sizes, int n_in,
                              void* d_out, int out_size, void* d_ws, size_t ws_size,
                              hipStream_t stream)
{
    const float* x         = (const float*)d_in[0];
    const float* click     = (const float*)d_in[1];
    const float* h_c       = (const float*)d_in[2];
    const float* h_v       = (const float*)d_in[3];
    const float* s_c       = (const float*)d_in[4];
    const float* s_v       = (const float*)d_in[5];
    const int*   g_prev    = (const int*)d_in[6];
    const float* Wx_c      = (const float*)d_in[7];
    const float* bx_c      = (const float*)d_in[8];
    const float* Wh_c      = (const float*)d_in[9];
    const float* Wx_v      = (const float*)d_in[10];
    const float* bx_v      = (const float*)d_in[11];
    const float* Wh_v      = (const float*)d_in[12];
    const float* W_schat_c = (const float*)d_in[13];
    const float* W_schat_v = (const float*)d_in[14];
    const float* W_svhat_v = (const float*)d_in[15];
    const float* W_svhat_c = (const float*)d_in[16];
    const float* Wpc0 = (const float*)d_in[17];
    const float* bpc0 = (const float*)d_in[18];
    const float* Wpc1 = (const float*)d_in[19];
    const float* bpc1 = (const float*)d_in[20];
    const float* Wfcc = (const float*)d_in[21];
    const float* bfcc = (const float*)d_in[22];
    const float* Wpv0 = (const float*)d_in[23];
    const float* bpv0 = (const float*)d_in[24];
    const float* Wpv1 = (const float*)d_in[25];
    const float* bpv1 = (const float*)d_in[26];
    const float* Wfcv = (const float*)d_in[27];
    const float* bfcv = (const float*)d_in[28];

    // output layout (fp32, concatenated in return order)
    float* out     = (float*)d_out;
    float* out_hcp = out;
    float* out_hvp = out + NB;
    float* out_hcn = out + 2 * NB;
    float* out_hvn = out_hcn + NB * NU;
    float* out_scn = out_hvn + NB * NU;
    float* out_svn = out_scn + NB * NU;
    float* out_gnw = out_svn + NB * NU;

    // workspace carve (bf16 elements), ~99 MB
    bf16* w = (bf16*)d_ws;
    bf16* WTc    = w; w += 256 * 256;        // W_schat_c^T
    bf16* WTv    = w; w += 256 * 256;        // W_schat_v^T
    bf16* Wsv    = w; w += 256 * 512;        // [W_svhat_v ; W_svhat_c]^T concat-K
    bf16* WT_pc0 = w; w += 128 * 256;
    bf16* WT_pv0 = w; w += 128 * 256;
    bf16* WT_pc1 = w; w += 64 * 128;
    bf16* WT_pv1 = w; w += 64 * 128;
    bf16* WgT_c  = w; w += 4 * 256 * 512;
    bf16* WgT_v  = w; w += 4 * 256 * 512;
    bf16* xs     = w; w += NB * 512;         // [x_bf | s_hat] (both branches)
    bf16* hv_cat = w; w += NB * 512;         // [h_v_bf | click-masked h_c_n]
    bf16* buf256 = w; w += NB * 256;         // h_c_bf -> hcnb -> hvnb (aliased)
    bf16* bufP0  = w; w += NB * 128;
    bf16* bufP1  = w; w += NB * 64;

    // --- weight prep jobs ---
    TrJobs J;
    int j = 0;
    // schat weights (n=v, k=u; dstr 256)
    J.src[j] = W_schat_c; J.dst[j] = WTc; J.R[j] = 256; J.C[j] = 256; J.dstr[j] = 256; ++j;
    J.src[j] = W_schat_v; J.dst[j] = WTv; J.R[j] = 256; J.C[j] = 256; J.dstr[j] = 256; ++j;
    // svhat concat weight (n=v, k<256: Wv, k>=256: Wc; dstr 512)
    J.src[j] = W_svhat_v; J.dst[j] = Wsv;       J.R[j] = 256; J.C[j] = 256; J.dstr[j] = 512; ++j;
    J.src[j] = W_svhat_c; J.dst[j] = Wsv + 256; J.R[j] = 256; J.C[j] = 256; J.dstr[j] = 512; ++j;
    // MLP weights
    J.src[j] = Wpc0; J.dst[j] = WT_pc0; J.R[j] = 256; J.C[j] = 128; J.dstr[j] = 256; ++j;
    J.src[j] = Wpv0; J.dst[j] = WT_pv0; J.R[j] = 256; J.C[j] = 128; J.dstr[j] = 256; ++j;
    J.src[j] = Wpc1; J.dst[j] = WT_pc1; J.R[j] = 128; J.C[j] = 64;  J.dstr[j] = 128; ++j;
    J.src[j] = Wpv1; J.dst[j] = WT_pv1; J.R[j] = 128; J.C[j] = 64;  J.dstr[j] = 128; ++j;
    // gate concat weights: WgT[(g*256+u)*512 + k], k<256: Wx[g][k][u], else Wh
    for (int g = 0; g < 4; ++g) {
        J.src[j] = Wx_c + g * 65536; J.dst[j] = WgT_c + g * 131072;       J.R[j] = 256; J.C[j] = 256; J.dstr[j] = 512; ++j;
        J.src[j] = Wh_c + g * 65536; J.dst[j] = WgT_c + g * 131072 + 256; J.R[j] = 256; J.C[j] = 256; J.dstr[j] = 512; ++j;
    }
    for (int g = 0; g < 4; ++g) {
        J.src[j] = Wx_v + g * 65536; J.dst[j] = WgT_v + g * 131072;       J.R[j] = 256; J.C[j] = 256; J.dstr[j] = 512; ++j;
        J.src[j] = Wh_v + g * 65536; J.dst[j] = WgT_v + g * 131072 + 256; J.R[j] = 256; J.C[j] = 256; J.dstr[j] = 512; ++j;
    }

    k_cvt<<<dim3(4096, 3), 256, 0, stream>>>(x, h_v, h_c, xs, hv_cat, buf256);
    k_tr<<<dim3(64, 24), dim3(32, 8), 0, stream>>>(J);

    // click branch
    k_schat_t<<<dim3(256, 4), 256, 0, stream>>>(buf256, hv_cat, WTc, WTv, g_prev, xs);
    k_gates_t<<<dim3(256, 8), 256, 0, stream>>>(xs, WgT_c, bx_c, click, g_prev, s_c,
                                                nullptr, out_scn, out_hcn, nullptr,
                                                buf256, hv_cat, 0);
    k_mlp_t<<<dim3(256, 2), 256, 0, stream>>>(buf256, 256, 8, WT_pc0, bpc0, bufP0, 128);
    k_mlp_t<<<dim3(256, 1), 256, 0, stream>>>(bufP0, 128, 4, WT_pc1, bpc1, bufP1, 64);
    k_final<<<NB / 256, 256, 0, stream>>>(bufP1, Wfcc, bfcc, nullptr, out_hcp);

    // conversion branch
    k_svhat_t<<<dim3(256, 2), 256, 0, stream>>>(hv_cat, Wsv, xs);
    k_gates_t<<<dim3(256, 8), 256, 0, stream>>>(xs, WgT_v, bx_v, click, nullptr, s_v,
                                                h_v, out_svn, out_hvn, out_gnw,
                                                buf256, nullptr, 1);
    k_mlp_t<<<dim3(256, 2), 256, 0, stream>>>(buf256, 256, 8, WT_pv0, bpv0, bufP0, 128);
    k_mlp_t<<<dim3(256, 1), 256, 0, stream>>>(bufP0, 128, 4, WT_pv1, bpv1, bufP1, 64);
    k_final<<<NB / 256, 256, 0, stream>>>(bufP1, Wfcv, bfcv, out_hcp, out_hvp);
}